// Round 12
// baseline (62.980 us; speedup 1.0000x reference)
//
#include <hip/hip_runtime.h>
#include <hip/hip_bf16.h>

#define N 2048
#define NL 1024
#define D 256
#define FPSCALE 16777216.0  // 2^24 fixed-point scale for deterministic atomics

using bfrag = __attribute__((ext_vector_type(8))) short;   // 8 bf16
using ffrag = __attribute__((ext_vector_type(4))) float;   // 4 f32 acc

__device__ inline float bf2f(ushort u) {
    union { unsigned int i; float f; } x;
    x.i = ((unsigned int)u) << 16;
    return x.f;
}
__device__ inline ushort f2bf(float f) {
    return __builtin_bit_cast(unsigned short, __float2bfloat16(f));
}
__device__ inline void atomic_fx(unsigned long long* acc, float v) {
    const long long q = (long long)((double)v * FPSCALE);
    atomicAdd(acc, (unsigned long long)q);
}

// ======== MAIN PATH ws layout (bytes), NEED = 13664256 ========
//   fB     [N*D]    ushort : 0
//   evG    [N*NL]   f32    : 1048576   (paired-view e sums)
//   gidxG  [NL*NL]  ushort : 9437184
//   rstG   [NL*NL]  ushort : 11534336
//   sq     [N]      f32    : 13631488
//   slab   [NL]     f32    : 13639680
//   sidx   [NL]     i32    : 13643776
//   rank   [NL]     i32    : 13647872
//   acc    u64            : 13651968
//   cnt    u32            : 13651976

__global__ __launch_bounds__(512) void k_prep3(
    const float* __restrict__ feat, const float* __restrict__ labels,
    ushort* __restrict__ fB, float* __restrict__ sq,
    float* __restrict__ slab, int* __restrict__ rank, int* __restrict__ sidx,
    unsigned long long* __restrict__ acc, unsigned int* __restrict__ cnt) {
    __shared__ float lab[NL];
    const int t = threadIdx.x;
    const int b = blockIdx.x;
    if (b < 2) {
        // counting-rank sort of the 1024 labels
        lab[t] = labels[t];
        lab[t + 512] = labels[t + 512];
        __syncthreads();
        const int j = b * 512 + t;
        const float lj = lab[j];
        int r = 0;
#pragma unroll 4
        for (int k = 0; k < NL; ++k) {
            const float lk = lab[k];
            r += (lk < lj) ? 1 : ((lk == lj && k < j) ? 1 : 0);
        }
        slab[r] = lj;
        sidx[r] = j;
        rank[j] = r;
        return;
    }
    if (b == 2 && t == 0) { *acc = 0ULL; *cnt = 0u; }  // zero fixed-point state each call
    // bf16 convert + row square-norms: 8 rows per block, one per wave
    const int l = t & 63;
    const int row = (b - 2) * 8 + (t >> 6);
    const float4 v = ((const float4*)(feat + (row & 1023) * 512 + (row >> 10) * 256))[l];
    float s = v.x * v.x + v.y * v.y + v.z * v.z + v.w * v.w;
#pragma unroll
    for (int off = 32; off; off >>= 1) s += __shfl_down(s, off);
    if (l == 0) sq[row] = s;
    ushort4 o;
    o.x = f2bf(v.x); o.y = f2bf(v.y); o.z = f2bf(v.z); o.w = f2bf(v.w);
    ((ushort4*)(fB + row * D))[l] = o;
}

// b < 128 : T role — per-label merge tables (validated r6-r11).
// b >= 128: G role — LDS-staged double-buffered MFMA gram (validated r11).
__global__ __launch_bounds__(512) void k_TG(
    const ushort* __restrict__ fB, const float* __restrict__ sq,
    const float* __restrict__ slab, const int* __restrict__ sidx,
    const int* __restrict__ rank,
    float* __restrict__ evG, ushort* __restrict__ gidxG, ushort* __restrict__ rstG,
    unsigned long long* __restrict__ acc) {
    const int b = blockIdx.x;
    const int t = threadIdx.x;
    const int l = t & 63, w = t >> 6;

    if (b < 128) {
        // ======================= T role =======================
        __shared__ float slb[NL];
        __shared__ int sx[NL];
        ((float2*)slb)[t] = ((const float2*)slab)[t];
        ((int2*)sx)[t] = ((const int2*)sidx)[t];
        __syncthreads();
        const int oi = b * 8 + w;
        const int pc = rank[oi];
        const float labi = slb[pc];
        const int nA = pc, nB = NL - pc;
        const int d = 16 * l;
        int alo = max(0, d - nB), ahi = min(d, nA);
        while (alo < ahi) {
            const int amid = (alo + ahi) >> 1;
            const float Av = labi - slb[pc - 1 - amid];
            const float Bv = slb[pc + (d - amid - 1)] - labi;
            if (Bv > Av) alo = amid + 1; else ahi = amid;
        }
        int a = alo, c = d - alo;
        int permp[16];
        float vals[16];
#pragma unroll
        for (int q = 0; q < 16; ++q) {
            const bool hasA = (a < nA), hasB = (c < nB);
            const float Av = hasA ? (labi - slb[pc - 1 - a]) : 0.f;
            const float Bv = hasB ? (slb[pc + c] - labi) : 0.f;
            const bool takeB = hasB && (!hasA || Bv <= Av);
            if (takeB) { permp[q] = pc + c;     vals[q] = Bv; ++c; }
            else       { permp[q] = pc - 1 - a; vals[q] = Av; ++a; }
        }
        const float pv0 = __shfl_up(vals[15], 1);
        int rs[16];
        int run = 0;
#pragma unroll
        for (int q = 0; q < 16; ++q) {
            const float pv = (q == 0) ? pv0 : vals[q - 1];
            const bool nr = (q == 0 && l == 0) ? false : (vals[q] != pv);
            if (nr) run = d + q;
            rs[q] = run;
        }
        int inc = run;
#pragma unroll
        for (int off = 1; off < 64; off <<= 1) {
            const int u = __shfl_up(inc, off);
            if (l >= off) inc = max(inc, u);
        }
        int excl = __shfl_up(inc, 1);
        if (l == 0) excl = 0;
        unsigned gp[8], rp[8];
#pragma unroll
        for (int q = 0; q < 8; ++q) {
            const unsigned g0 = (unsigned)sx[permp[2 * q]];
            const unsigned g1 = (unsigned)sx[permp[2 * q + 1]];
            gp[q] = g0 | (g1 << 16);
            const unsigned r0 = (unsigned)max(rs[2 * q], excl);
            const unsigned r1 = (unsigned)max(rs[2 * q + 1], excl);
            rp[q] = r0 | (r1 << 16);
        }
        uint4* gdst = (uint4*)(gidxG + (size_t)oi * NL + d);
        uint4* rdst = (uint4*)(rstG + (size_t)oi * NL + d);
        gdst[0] = make_uint4(gp[0], gp[1], gp[2], gp[3]);
        gdst[1] = make_uint4(gp[4], gp[5], gp[6], gp[7]);
        rdst[0] = make_uint4(rp[0], rp[1], rp[2], rp[3]);
        rdst[1] = make_uint4(rp[4], rp[5], rp[6], rp[7]);
        return;
    }

    // ======================= G role (r11 k_G2) =======================
    {
        __shared__ __align__(16) ushort sA[2][128 * 32];
        __shared__ __align__(16) ushort sB[2][2][64 * 32];
        __shared__ float sqr[128], sc0[64], sc1[64];
        __shared__ float red[8];
        const int gb = b - 128;            // 0..255
        const int row0 = (gb >> 4) * 128;
        const int c0 = (gb & 15) * 64;
        const int rw = w >> 1, pw = w & 1;
        const int lm = l & 15, g = l >> 4;

        const int rowA = t >> 2, kchunk = (t & 3) * 8;
        const ushort* srcA = fB + (size_t)(row0 + rowA) * D + kchunk;
        const int isB1 = t >> 8;
        const int rowB = (t & 255) >> 2;
        const ushort* srcB = fB + (size_t)((isB1 ? 1024 + c0 : c0) + rowB) * D + kchunk;

        if (t < 128) sqr[t] = sq[row0 + t];
        else if (t < 192) sc0[t - 128] = sq[c0 + (t - 128)];
        else if (t < 256) sc1[t - 192] = sq[1024 + c0 + (t - 192)];

        uint4 rA = *(const uint4*)srcA;
        uint4 rB = *(const uint4*)srcB;
        *(uint4*)&sA[0][t * 8] = rA;
        *(uint4*)&sB[0][isB1][(t & 255) * 8] = rB;
        rA = *(const uint4*)(srcA + 32);
        rB = *(const uint4*)(srcB + 32);
        __syncthreads();

        ffrag acc4[2][2][2];
#pragma unroll
        for (int ar = 0; ar < 2; ++ar)
#pragma unroll
            for (int br = 0; br < 2; ++br)
#pragma unroll
                for (int vv = 0; vv < 2; ++vv)
                    acc4[ar][br][vv] = (ffrag){0.f, 0.f, 0.f, 0.f};

        for (int s = 0; s < 8; ++s) {
            const int buf = s & 1;
            const bfrag a0 = *(const bfrag*)&sA[buf][(rw * 32 + lm) * 32 + g * 8];
            const bfrag a1 = *(const bfrag*)&sA[buf][(rw * 32 + 16 + lm) * 32 + g * 8];
            const bfrag b00 = *(const bfrag*)&sB[buf][0][(pw * 32 + lm) * 32 + g * 8];
            const bfrag b01 = *(const bfrag*)&sB[buf][0][(pw * 32 + 16 + lm) * 32 + g * 8];
            const bfrag b10 = *(const bfrag*)&sB[buf][1][(pw * 32 + lm) * 32 + g * 8];
            const bfrag b11 = *(const bfrag*)&sB[buf][1][(pw * 32 + 16 + lm) * 32 + g * 8];
            acc4[0][0][0] = __builtin_amdgcn_mfma_f32_16x16x32_bf16(a0, b00, acc4[0][0][0], 0, 0, 0);
            acc4[0][1][0] = __builtin_amdgcn_mfma_f32_16x16x32_bf16(a0, b01, acc4[0][1][0], 0, 0, 0);
            acc4[1][0][0] = __builtin_amdgcn_mfma_f32_16x16x32_bf16(a1, b00, acc4[1][0][0], 0, 0, 0);
            acc4[1][1][0] = __builtin_amdgcn_mfma_f32_16x16x32_bf16(a1, b01, acc4[1][1][0], 0, 0, 0);
            acc4[0][0][1] = __builtin_amdgcn_mfma_f32_16x16x32_bf16(a0, b10, acc4[0][0][1], 0, 0, 0);
            acc4[0][1][1] = __builtin_amdgcn_mfma_f32_16x16x32_bf16(a0, b11, acc4[0][1][1], 0, 0, 0);
            acc4[1][0][1] = __builtin_amdgcn_mfma_f32_16x16x32_bf16(a1, b10, acc4[1][0][1], 0, 0, 0);
            acc4[1][1][1] = __builtin_amdgcn_mfma_f32_16x16x32_bf16(a1, b11, acc4[1][1][1], 0, 0, 0);
            if (s < 7) {
                __syncthreads();
                *(uint4*)&sA[buf ^ 1][t * 8] = rA;
                *(uint4*)&sB[buf ^ 1][isB1][(t & 255) * 8] = rB;
                if (s < 6) {
                    rA = *(const uint4*)(srcA + (s + 2) * 32);
                    rB = *(const uint4*)(srcB + (s + 2) * 32);
                }
                __syncthreads();
            }
        }

        float contrib = 0.f;
#pragma unroll
        for (int ar = 0; ar < 2; ++ar) {
#pragma unroll
            for (int br = 0; br < 2; ++br) {
                const int c = c0 + pw * 32 + br * 16 + lm;
                const float sj0 = sc0[c - c0];
                const float sj1 = sc1[c - c0];
#pragma unroll
                for (int v = 0; v < 4; ++v) {
                    const int gi = row0 + rw * 32 + ar * 16 + g * 4 + v;
                    const float sqi = sqr[gi - row0];
                    const float d20 = sqi + sj0 - 2.f * acc4[ar][br][0][v];
                    const float d21 = sqi + sj1 - 2.f * acc4[ar][br][1][v];
                    const float lg0 = -0.5f * sqrtf(fmaxf(d20, 0.f));
                    const float lg1 = -0.5f * sqrtf(fmaxf(d21, 0.f));
                    const bool dg0 = (c == gi), dg1 = (1024 + c == gi);
                    const float e0 = dg0 ? 0.f : expf(lg0);
                    const float e1 = dg1 ? 0.f : expf(lg1);
                    if (!dg0) contrib += lg0;
                    if (!dg1) contrib += lg1;
                    evG[(size_t)gi * NL + c] = e0 + e1;
                }
            }
        }

#pragma unroll
        for (int off = 32; off; off >>= 1) contrib += __shfl_xor(contrib, off);
        if (l == 0) red[w] = contrib;
        __syncthreads();
        if (t == 0) {
            float sb = 0.f;
#pragma unroll
            for (int q = 0; q < 8; ++q) sb += red[q];
            atomic_fx(acc, sb);
        }
    }
}

// wave = one oi, BOTH rows (oi, oi+1024): tables loaded once, 2 gathers/scans with ILP.
// Last block converts the fixed-point accumulator and writes the loss.
__global__ __launch_bounds__(256) void k_S4(
    const float* __restrict__ evG, const ushort* __restrict__ gidxG,
    const ushort* __restrict__ rstG,
    unsigned long long* __restrict__ acc, unsigned int* __restrict__ cnt,
    float* __restrict__ out) {
    const int b = blockIdx.x;          // 256
    const int t = threadIdx.x;         // 256 = 4 waves
    const int l = t & 63, w = t >> 6;
    const int oi = 4 * b + w;

    __shared__ float evs[4][2][NL];    // 32 KB
    __shared__ float red[4];

    // issue all global loads
    const float4* p0 = (const float4*)(evG + (size_t)oi * NL);
    const float4* p1 = (const float4*)(evG + (size_t)(oi + 1024) * NL);
    float4 e0[4], e1[4];
#pragma unroll
    for (int c = 0; c < 4; ++c) { e0[c] = p0[l * 4 + c]; e1[c] = p1[l * 4 + c]; }
    const uint4 g0 = ((const uint4*)(gidxG + (size_t)oi * NL))[2 * l];
    const uint4 g1 = ((const uint4*)(gidxG + (size_t)oi * NL))[2 * l + 1];
    const uint4 r0 = ((const uint4*)(rstG + (size_t)oi * NL))[2 * l];
    const uint4 r1 = ((const uint4*)(rstG + (size_t)oi * NL))[2 * l + 1];

    // sigma-swizzled stores: value j -> addr (j&15)*64 + (j>>4); j = l*16 + (c*4+u)
#pragma unroll
    for (int c = 0; c < 4; ++c) {
        evs[w][0][(c * 4 + 0) * 64 + l] = e0[c].x;
        evs[w][0][(c * 4 + 1) * 64 + l] = e0[c].y;
        evs[w][0][(c * 4 + 2) * 64 + l] = e0[c].z;
        evs[w][0][(c * 4 + 3) * 64 + l] = e0[c].w;
        evs[w][1][(c * 4 + 0) * 64 + l] = e1[c].x;
        evs[w][1][(c * 4 + 1) * 64 + l] = e1[c].y;
        evs[w][1][(c * 4 + 2) * 64 + l] = e1[c].z;
        evs[w][1][(c * 4 + 3) * 64 + l] = e1[c].w;
    }

    int gx[16], rs[16];
    {
        const unsigned gw[8] = {g0.x, g0.y, g0.z, g0.w, g1.x, g1.y, g1.z, g1.w};
        const unsigned rw[8] = {r0.x, r0.y, r0.z, r0.w, r1.x, r1.y, r1.z, r1.w};
#pragma unroll
        for (int q = 0; q < 8; ++q) {
            gx[2 * q] = gw[q] & 0xffff; gx[2 * q + 1] = gw[q] >> 16;
            rs[2 * q] = rw[q] & 0xffff; rs[2 * q + 1] = rw[q] >> 16;
        }
    }

    // gather both rows in merge order (same-wave DS in-order; all reads precede E writes)
    float v0[16], v1[16], pre0[16], pre1[16];
#pragma unroll
    for (int q = 0; q < 16; ++q) {
        const int a = ((gx[q] & 15) << 6) | (gx[q] >> 4);
        v0[q] = evs[w][0][a];
        v1[q] = evs[w][1][a];
    }
    float run0 = 0.f, run1 = 0.f;
#pragma unroll
    for (int q = 0; q < 16; ++q) {
        pre0[q] = run0; run0 += v0[q];
        pre1[q] = run1; run1 += v1[q];
    }
    float i0 = run0, i1 = run1;
#pragma unroll
    for (int off = 1; off < 64; off <<= 1) {
        const float u0 = __shfl_up(i0, off);
        const float u1 = __shfl_up(i1, off);
        if (l >= off) { i0 += u0; i1 += u1; }
    }
    const float tot0 = __shfl(i0, 63), tot1 = __shfl(i1, 63);
    const float base0 = i0 - run0, base1 = i1 - run1;
    // overwrite with exclusive prefix E (merge rank m = l*16+q -> addr q*64+l)
#pragma unroll
    for (int q = 0; q < 16; ++q) {
        evs[w][0][q * 64 + l] = base0 + pre0[q];
        evs[w][1][q * 64 + l] = base1 + pre1[q];
    }

    float contrib = 0.f;
#pragma unroll
    for (int q = 0; q < 16; ++q) {
        const int m = rs[q];
        const int a = ((m & 15) << 6) | (m >> 4);
        const float dn0 = tot0 - evs[w][0][a];
        const float dn1 = tot1 - evs[w][1][a];
        const float m2 = (gx[q] == oi) ? 1.f : 2.f;
        contrib -= m2 * (__logf(dn0) + __logf(dn1));
    }

#pragma unroll
    for (int off = 32; off; off >>= 1) contrib += __shfl_xor(contrib, off);
    if (l == 0) red[w] = contrib;
    __syncthreads();
    if (t == 0) {
        atomic_fx(acc, red[0] + red[1] + red[2] + red[3]);
        __threadfence();
        const unsigned done = atomicAdd(cnt, 1u);
        if (done == 255u) {
            const unsigned long long raw = atomicAdd(acc, 0ULL);
            const double tot = (double)(long long)raw / FPSCALE;
            out[0] = (float)(-tot / ((double)N * (double)(N - 1)));
        }
    }
}

// ================= FALLBACK PATH (round-5 fused, ~1.07 MB ws, proven) =================

__global__ __launch_bounds__(512) void k_prep_fb(
    const float* __restrict__ feat, const float* __restrict__ labels,
    ushort* __restrict__ fB, float* __restrict__ sq,
    float* __restrict__ slab, int* __restrict__ rank, int* __restrict__ sidx) {
    __shared__ float lab[NL];
    const int t = threadIdx.x;
    const int b = blockIdx.x;
    if (b < 2) {
        lab[t] = labels[t];
        lab[t + 512] = labels[t + 512];
        __syncthreads();
        const int j = b * 512 + t;
        const float lj = lab[j];
        int r = 0;
#pragma unroll 4
        for (int k = 0; k < NL; ++k) {
            const float lk = lab[k];
            r += (lk < lj) ? 1 : ((lk == lj && k < j) ? 1 : 0);
        }
        slab[r] = lj;
        sidx[r] = j;
        rank[j] = r;
        return;
    }
    const int l = t & 63;
    const int row = (b - 2) * 8 + (t >> 6);
    const float4 v = ((const float4*)(feat + (row & 1023) * 512 + (row >> 10) * 256))[l];
    float s = v.x * v.x + v.y * v.y + v.z * v.z + v.w * v.w;
#pragma unroll
    for (int off = 32; off; off >>= 1) s += __shfl_down(s, off);
    if (l == 0) sq[row] = s;
    ushort4 o;
    o.x = f2bf(v.x); o.y = f2bf(v.y); o.z = f2bf(v.z); o.w = f2bf(v.w);
    ((ushort4*)(fB + row * D))[l] = o;
}

__global__ __launch_bounds__(512) void k_fused(
    const ushort* __restrict__ fB, const float* __restrict__ sq,
    const float* __restrict__ slab, const int* __restrict__ sidx,
    const int* __restrict__ rank, const float* __restrict__ labels,
    float* __restrict__ bsum) {
    const int b = blockIdx.x;
    const int t = threadIdx.x;
    const int l = t & 63, w = t >> 6;
    const int tile0 = (b >> 1) * 16;
    const int half = b & 1;
    const int i0 = b * 8;

    __shared__ __align__(16) ushort erow[8][2048];
    __shared__ __align__(16) float slb[NL];
    __shared__ __align__(16) int sx[NL];
    __shared__ float red[8];

    ((float2*)slb)[t] = ((const float2*)slab)[t];
    ((int2*)sx)[t] = ((const int2*)sidx)[t];

    float contrib = 0.f;
    const int ko = (l >> 4) * 8;
    const ushort* arow = fB + (tile0 + (l & 15)) * D + ko;
    const int rg = l >> 4;

#pragma unroll
    for (int cp = 0; cp < 2; ++cp) {
        const int colbase = cp * 1024 + w * 128;
        const ushort* brow = fB + (colbase + (l & 15)) * D + ko;
        ffrag acc[8];
#pragma unroll
        for (int n = 0; n < 8; ++n) acc[n] = (ffrag){0.f, 0.f, 0.f, 0.f};
#pragma unroll
        for (int kk = 0; kk < 8; ++kk) {
            const bfrag a = *(const bfrag*)(arow + kk * 32);
#pragma unroll
            for (int n = 0; n < 8; ++n) {
                const bfrag bb = *(const bfrag*)(brow + n * 16 * D + kk * 32);
                acc[n] = __builtin_amdgcn_mfma_f32_16x16x32_bf16(a, bb, acc[n], 0, 0, 0);
            }
        }
        if ((rg >> 1) == half) {
#pragma unroll
            for (int v = 0; v < 4; ++v) {
                const int gi = tile0 + rg * 4 + v;
                const int r = gi - i0;
                const float sqi = sq[gi];
#pragma unroll
                for (int n = 0; n < 8; ++n) {
                    const int gj = colbase + n * 16 + (l & 15);
                    const float d2 = sqi + sq[gj] - 2.f * acc[n][v];
                    const float lg = -0.5f * sqrtf(fmaxf(d2, 0.f));
                    const bool diag = (gj == gi);
                    const float e = diag ? 0.f : expf(lg);
                    if (!diag) contrib += lg;
                    erow[r][gj] = f2bf(e);
                }
            }
        }
    }
    __syncthreads();

    const int gi = i0 + w;
    const int oi = gi & 1023;
    const float labi = labels[oi];
    const int pc = rank[oi];

    int sxv[16];
    float val[16], pre[16];
    const ushort* er = &erow[w][0];
#pragma unroll
    for (int c = 0; c < 4; ++c) {
        const int4 s4 = ((const int4*)sx)[l * 4 + c];
        sxv[c * 4 + 0] = s4.x; sxv[c * 4 + 1] = s4.y;
        sxv[c * 4 + 2] = s4.z; sxv[c * 4 + 3] = s4.w;
        val[c * 4 + 0] = bf2f(er[s4.x]) + bf2f(er[s4.x + 1024]);
        val[c * 4 + 1] = bf2f(er[s4.y]) + bf2f(er[s4.y + 1024]);
        val[c * 4 + 2] = bf2f(er[s4.z]) + bf2f(er[s4.z + 1024]);
        val[c * 4 + 3] = bf2f(er[s4.w]) + bf2f(er[s4.w + 1024]);
    }
    float run = 0.f;
#pragma unroll
    for (int q = 0; q < 16; ++q) { pre[q] = run; run += val[q]; }
    float inc = run;
#pragma unroll
    for (int off = 1; off < 64; off <<= 1) {
        const float u = __shfl_up(inc, off);
        if (l >= off) inc += u;
    }
    const float tot = __shfl(inc, 63);
    const float base = inc - run;
    float* E = (float*)&erow[w][0];
#pragma unroll
    for (int c = 0; c < 4; ++c) {
        float4 o;
        o.x = base + pre[c * 4 + 0];
        o.y = base + pre[c * 4 + 1];
        o.z = base + pre[c * 4 + 2];
        o.w = base + pre[c * 4 + 3];
        ((float4*)&E[l * 16])[c] = o;
    }

    const int lim = NL - pc;
#pragma unroll
    for (int q = 0; q < 16; ++q) {
        const int p = l * 16 + q;
        const float tq = fabsf(labi - slb[p]);
        int lo = 0;
#pragma unroll
        for (int step = 512; step; step >>= 1) {
            const int cand = lo + step;
            const int ix = max(min(cand - 1, pc - 1), 0);
            const bool ok = (cand <= pc) && (fabsf(labi - slb[ix]) >= tq);
            lo = ok ? cand : lo;
        }
        int hi = 0;
#pragma unroll
        for (int step = 512; step; step >>= 1) {
            const int cand = hi + step;
            const int ix = min(pc + cand - 1, NL - 1);
            const bool ok = (cand <= lim) && (fabsf(labi - slb[ix]) < tq);
            hi = ok ? cand : hi;
        }
        const int hl = pc + hi;
        const float Eh = (hl == NL) ? tot : E[hl];
        const float dn = tot - (Eh - E[lo]);
        const float m2 = (sxv[q] == oi) ? 1.f : 2.f;
        contrib -= m2 * logf(dn);
    }

#pragma unroll
    for (int off = 32; off; off >>= 1) contrib += __shfl_xor(contrib, off);
    if (l == 0) red[w] = contrib;
    __syncthreads();
    if (t == 0) {
        float sb = 0.f;
#pragma unroll
        for (int q = 0; q < 8; ++q) sb += red[q];
        bsum[b] = sb;
    }
}

__global__ void k_final_fb(const float* __restrict__ bs, float* __restrict__ out) {
    __shared__ double rd[4];
    const int t = threadIdx.x;
    double s = (double)bs[t];
#pragma unroll
    for (int off = 32; off; off >>= 1) s += __shfl_down(s, off);
    if ((t & 63) == 0) rd[t >> 6] = s;
    __syncthreads();
    if (t == 0) {
        const double tot = rd[0] + rd[1] + rd[2] + rd[3];
        out[0] = (float)(-tot / ((double)N * (double)(N - 1)));
    }
}

extern "C" void kernel_launch(void* const* d_in, const int* in_sizes, int n_in,
                              void* d_out, int out_size, void* d_ws, size_t ws_size,
                              hipStream_t stream) {
    const float* feat = (const float*)d_in[0];
    const float* labels = (const float*)d_in[1];
    char* ws = (char*)d_ws;

    if (ws_size >= 13664256ULL) {
        ushort* fB = (ushort*)ws;
        float* evG = (float*)(ws + 1048576);
        ushort* gidxG = (ushort*)(ws + 9437184);
        ushort* rstG = (ushort*)(ws + 11534336);
        float* sq = (float*)(ws + 13631488);
        float* slab = (float*)(ws + 13639680);
        int* sidx = (int*)(ws + 13643776);
        int* rank = (int*)(ws + 13647872);
        unsigned long long* acc = (unsigned long long*)(ws + 13651968);
        unsigned int* cnt = (unsigned int*)(ws + 13651976);

        k_prep3<<<258, 512, 0, stream>>>(feat, labels, fB, sq, slab, rank, sidx, acc, cnt);
        k_TG<<<384, 512, 0, stream>>>(fB, sq, slab, sidx, rank, evG, gidxG, rstG, acc);
        k_S4<<<256, 256, 0, stream>>>(evG, gidxG, rstG, acc, cnt, (float*)d_out);
    } else {
        ushort* fB = (ushort*)ws;
        float* sq = (float*)(ws + 1048576);
        float* slab = (float*)(ws + 1056768);
        int* sidx = (int*)(ws + 1060864);
        int* rank = (int*)(ws + 1064960);
        float* bsum = (float*)(ws + 1069056);

        k_prep_fb<<<258, 512, 0, stream>>>(feat, labels, fB, sq, slab, rank, sidx);
        k_fused<<<256, 512, 0, stream>>>(fB, sq, slab, sidx, rank, labels, bsum);
        k_final_fb<<<1, 256, 0, stream>>>(bsum, (float*)d_out);
    }
}

// Round 13
// 41.372 us; speedup vs baseline: 1.5223x; 1.5223x over previous
//
#include <hip/hip_runtime.h>
#include <hip/hip_bf16.h>

#define N 2048
#define NL 1024
#define D 256
#define FPSCALE 16777216.0  // 2^24 fixed-point scale for deterministic atomics

using bfrag = __attribute__((ext_vector_type(8))) short;   // 8 bf16
using ffrag = __attribute__((ext_vector_type(4))) float;   // 4 f32 acc

__device__ inline float bf2f(ushort u) {
    union { unsigned int i; float f; } x;
    x.i = ((unsigned int)u) << 16;
    return x.f;
}
__device__ inline ushort f2bf(float f) {
    return __builtin_bit_cast(unsigned short, __float2bfloat16(f));
}
__device__ inline void atomic_fx(unsigned long long* acc, float v) {
    const long long q = (long long)((double)v * FPSCALE);
    atomicAdd(acc, (unsigned long long)q);
}

// ======== MAIN PATH ws layout (bytes), NEED = 9457680 ========
//   fB    [N*D]  ushort : 0
//   evG   [N*NL] f32    : 1048576   (paired-view e sums)
//   sq    [N]    f32    : 9437184
//   slab  [NL]   f32    : 9445376
//   sidx  [NL]   i32    : 9449472
//   rank  [NL]   i32    : 9453568
//   acc   u64           : 9457664
//   cnt   u32           : 9457672

__global__ __launch_bounds__(512) void k_prep4(
    const float* __restrict__ feat, const float* __restrict__ labels,
    ushort* __restrict__ fB, float* __restrict__ sq,
    float* __restrict__ slab, int* __restrict__ rank, int* __restrict__ sidx,
    unsigned long long* __restrict__ acc, unsigned int* __restrict__ cnt) {
    const int t = threadIdx.x;
    const int b = blockIdx.x;
    if (b < 16) {
        // parallel counting-rank sort: block owns 64 j's x 8 chunks of 128 labels
        __shared__ float lab[NL];
        __shared__ int part[64][9];
        ((float2*)lab)[t] = ((const float2*)labels)[t];
        __syncthreads();
        const int jl = t >> 3, ch = t & 7;
        const int j = b * 64 + jl;
        const float lj = lab[j];
        const int k0 = ch * 128;
        int r = 0;
#pragma unroll 4
        for (int k = k0; k < k0 + 128; ++k) {
            const float lk = lab[k];
            r += (lk < lj) ? 1 : ((lk == lj && k < j) ? 1 : 0);
        }
        part[jl][ch] = r;
        __syncthreads();
        if (t < 64) {
            const int jj = b * 64 + t;
            int rr = 0;
#pragma unroll
            for (int q = 0; q < 8; ++q) rr += part[t][q];
            slab[rr] = lab[jj];
            sidx[rr] = jj;
            rank[jj] = rr;
        }
        return;
    }
    if (b == 16 && t == 0) { *acc = 0ULL; *cnt = 0u; }  // zero fixed-point state each call
    // bf16 convert + row square-norms: 8 rows per block, one per wave
    const int l = t & 63;
    const int row = (b - 16) * 8 + (t >> 6);
    const float4 v = ((const float4*)(feat + (row & 1023) * 512 + (row >> 10) * 256))[l];
    float s = v.x * v.x + v.y * v.y + v.z * v.z + v.w * v.w;
#pragma unroll
    for (int off = 32; off; off >>= 1) s += __shfl_down(s, off);
    if (l == 0) sq[row] = s;
    ushort4 o;
    o.x = f2bf(v.x); o.y = f2bf(v.y); o.z = f2bf(v.z); o.w = f2bf(v.w);
    ((ushort4*)(fB + row * D))[l] = o;
}

// LDS-staged double-buffered MFMA gram (validated r11/r12): 256 blocks x 8 waves,
// block tile = 128 rows x 64 col-pairs (views paired), K in 8 slices of 32.
__global__ __launch_bounds__(512) void k_G(
    const ushort* __restrict__ fB, const float* __restrict__ sq,
    float* __restrict__ evG, unsigned long long* __restrict__ acc) {
    const int gb = blockIdx.x;         // 256
    const int t = threadIdx.x;         // 512 = 8 waves
    const int l = t & 63, w = t >> 6;
    const int row0 = (gb >> 4) * 128;
    const int c0 = (gb & 15) * 64;
    const int rw = w >> 1, pw = w & 1;
    const int lm = l & 15, g = l >> 4;

    __shared__ __align__(16) ushort sA[2][128 * 32];
    __shared__ __align__(16) ushort sB[2][2][64 * 32];
    __shared__ float sqr[128], sc0[64], sc1[64];
    __shared__ float red[8];

    const int rowA = t >> 2, kchunk = (t & 3) * 8;
    const ushort* srcA = fB + (size_t)(row0 + rowA) * D + kchunk;
    const int isB1 = t >> 8;
    const int rowB = (t & 255) >> 2;
    const ushort* srcB = fB + (size_t)((isB1 ? 1024 + c0 : c0) + rowB) * D + kchunk;

    if (t < 128) sqr[t] = sq[row0 + t];
    else if (t < 192) sc0[t - 128] = sq[c0 + (t - 128)];
    else if (t < 256) sc1[t - 192] = sq[1024 + c0 + (t - 192)];

    uint4 rA = *(const uint4*)srcA;
    uint4 rB = *(const uint4*)srcB;
    *(uint4*)&sA[0][t * 8] = rA;
    *(uint4*)&sB[0][isB1][(t & 255) * 8] = rB;
    rA = *(const uint4*)(srcA + 32);
    rB = *(const uint4*)(srcB + 32);
    __syncthreads();

    ffrag acc4[2][2][2];
#pragma unroll
    for (int ar = 0; ar < 2; ++ar)
#pragma unroll
        for (int br = 0; br < 2; ++br)
#pragma unroll
            for (int vv = 0; vv < 2; ++vv)
                acc4[ar][br][vv] = (ffrag){0.f, 0.f, 0.f, 0.f};

    for (int s = 0; s < 8; ++s) {
        const int buf = s & 1;
        const bfrag a0 = *(const bfrag*)&sA[buf][(rw * 32 + lm) * 32 + g * 8];
        const bfrag a1 = *(const bfrag*)&sA[buf][(rw * 32 + 16 + lm) * 32 + g * 8];
        const bfrag b00 = *(const bfrag*)&sB[buf][0][(pw * 32 + lm) * 32 + g * 8];
        const bfrag b01 = *(const bfrag*)&sB[buf][0][(pw * 32 + 16 + lm) * 32 + g * 8];
        const bfrag b10 = *(const bfrag*)&sB[buf][1][(pw * 32 + lm) * 32 + g * 8];
        const bfrag b11 = *(const bfrag*)&sB[buf][1][(pw * 32 + 16 + lm) * 32 + g * 8];
        acc4[0][0][0] = __builtin_amdgcn_mfma_f32_16x16x32_bf16(a0, b00, acc4[0][0][0], 0, 0, 0);
        acc4[0][1][0] = __builtin_amdgcn_mfma_f32_16x16x32_bf16(a0, b01, acc4[0][1][0], 0, 0, 0);
        acc4[1][0][0] = __builtin_amdgcn_mfma_f32_16x16x32_bf16(a1, b00, acc4[1][0][0], 0, 0, 0);
        acc4[1][1][0] = __builtin_amdgcn_mfma_f32_16x16x32_bf16(a1, b01, acc4[1][1][0], 0, 0, 0);
        acc4[0][0][1] = __builtin_amdgcn_mfma_f32_16x16x32_bf16(a0, b10, acc4[0][0][1], 0, 0, 0);
        acc4[0][1][1] = __builtin_amdgcn_mfma_f32_16x16x32_bf16(a0, b11, acc4[0][1][1], 0, 0, 0);
        acc4[1][0][1] = __builtin_amdgcn_mfma_f32_16x16x32_bf16(a1, b10, acc4[1][0][1], 0, 0, 0);
        acc4[1][1][1] = __builtin_amdgcn_mfma_f32_16x16x32_bf16(a1, b11, acc4[1][1][1], 0, 0, 0);
        if (s < 7) {
            __syncthreads();
            *(uint4*)&sA[buf ^ 1][t * 8] = rA;
            *(uint4*)&sB[buf ^ 1][isB1][(t & 255) * 8] = rB;
            if (s < 6) {
                rA = *(const uint4*)(srcA + (s + 2) * 32);
                rB = *(const uint4*)(srcB + (s + 2) * 32);
            }
            __syncthreads();
        }
    }

    float contrib = 0.f;
#pragma unroll
    for (int ar = 0; ar < 2; ++ar) {
#pragma unroll
        for (int br = 0; br < 2; ++br) {
            const int c = c0 + pw * 32 + br * 16 + lm;
            const float sj0 = sc0[c - c0];
            const float sj1 = sc1[c - c0];
#pragma unroll
            for (int v = 0; v < 4; ++v) {
                const int gi = row0 + rw * 32 + ar * 16 + g * 4 + v;
                const float sqi = sqr[gi - row0];
                const float d20 = sqi + sj0 - 2.f * acc4[ar][br][0][v];
                const float d21 = sqi + sj1 - 2.f * acc4[ar][br][1][v];
                const float lg0 = -0.5f * sqrtf(fmaxf(d20, 0.f));
                const float lg1 = -0.5f * sqrtf(fmaxf(d21, 0.f));
                const bool dg0 = (c == gi), dg1 = (1024 + c == gi);
                const float e0 = dg0 ? 0.f : expf(lg0);
                const float e1 = dg1 ? 0.f : expf(lg1);
                if (!dg0) contrib += lg0;
                if (!dg1) contrib += lg1;
                evG[(size_t)gi * NL + c] = e0 + e1;
            }
        }
    }

#pragma unroll
    for (int off = 32; off; off >>= 1) contrib += __shfl_xor(contrib, off);
    if (l == 0) red[w] = contrib;
    __syncthreads();
    if (t == 0) {
        float sb = 0.f;
#pragma unroll
        for (int q = 0; q < 8; ++q) sb += red[q];
        atomic_fx(acc, sb);
    }
}

// S with in-wave merge-table construction: wave = one oi, both rows (oi, oi+1024).
// The T computation (validated r6-r12) runs in the shadow of the evG load latency.
__global__ __launch_bounds__(256) void k_S5(
    const float* __restrict__ evG, const float* __restrict__ slab,
    const int* __restrict__ sidx, const int* __restrict__ rank,
    unsigned long long* __restrict__ acc, unsigned int* __restrict__ cnt,
    float* __restrict__ out) {
    const int b = blockIdx.x;          // 256
    const int t = threadIdx.x;         // 256 = 4 waves
    const int l = t & 63, w = t >> 6;
    const int oi = 4 * b + w;

    __shared__ float slb[NL];          // 4 KB
    __shared__ int sx[NL];             // 4 KB
    __shared__ float evs[4][2][NL];    // 32 KB
    __shared__ float red[4];

    // ---- issue evG loads first (latency hides under the T phase below)
    const float4* p0 = (const float4*)(evG + (size_t)oi * NL);
    const float4* p1 = (const float4*)(evG + (size_t)(oi + 1024) * NL);
    float4 e0[4], e1[4];
#pragma unroll
    for (int c = 0; c < 4; ++c) { e0[c] = p0[l * 4 + c]; e1[c] = p1[l * 4 + c]; }

    ((float4*)slb)[t] = ((const float4*)slab)[t];
    ((int4*)sx)[t] = ((const int4*)sidx)[t];
    __syncthreads();

    // ---- T phase (in registers): merge-path over the V-shaped ld arms
    const int pc = rank[oi];
    const float labi = slb[pc];
    const int nA = pc, nB = NL - pc;
    const int d = 16 * l;
    int alo = max(0, d - nB), ahi = min(d, nA);
    while (alo < ahi) {
        const int amid = (alo + ahi) >> 1;
        const float Av = labi - slb[pc - 1 - amid];
        const float Bv = slb[pc + (d - amid - 1)] - labi;
        if (Bv > Av) alo = amid + 1; else ahi = amid;
    }
    int a = alo, c = d - alo;
    int gx[16], rs[16];
    float vals[16];
#pragma unroll
    for (int q = 0; q < 16; ++q) {
        const bool hasA = (a < nA), hasB = (c < nB);
        const float Av = hasA ? (labi - slb[pc - 1 - a]) : 0.f;
        const float Bv = hasB ? (slb[pc + c] - labi) : 0.f;
        const bool takeB = hasB && (!hasA || Bv <= Av);
        int pp;
        if (takeB) { pp = pc + c;     vals[q] = Bv; ++c; }
        else       { pp = pc - 1 - a; vals[q] = Av; ++a; }
        gx[q] = sx[pp];
    }
    {
        const float pv0 = __shfl_up(vals[15], 1);
        int run = 0;
#pragma unroll
        for (int q = 0; q < 16; ++q) {
            const float pv = (q == 0) ? pv0 : vals[q - 1];
            const bool nr = (q == 0 && l == 0) ? false : (vals[q] != pv);
            if (nr) run = d + q;
            rs[q] = run;
        }
        int incr = run;
#pragma unroll
        for (int off = 1; off < 64; off <<= 1) {
            const int u = __shfl_up(incr, off);
            if (l >= off) incr = max(incr, u);
        }
        int excl = __shfl_up(incr, 1);
        if (l == 0) excl = 0;
#pragma unroll
        for (int q = 0; q < 16; ++q) rs[q] = max(rs[q], excl);
    }

    // ---- sigma-swizzled ev stores: value j -> addr (j&15)*64 + (j>>4)
#pragma unroll
    for (int c2 = 0; c2 < 4; ++c2) {
        evs[w][0][(c2 * 4 + 0) * 64 + l] = e0[c2].x;
        evs[w][0][(c2 * 4 + 1) * 64 + l] = e0[c2].y;
        evs[w][0][(c2 * 4 + 2) * 64 + l] = e0[c2].z;
        evs[w][0][(c2 * 4 + 3) * 64 + l] = e0[c2].w;
        evs[w][1][(c2 * 4 + 0) * 64 + l] = e1[c2].x;
        evs[w][1][(c2 * 4 + 1) * 64 + l] = e1[c2].y;
        evs[w][1][(c2 * 4 + 2) * 64 + l] = e1[c2].z;
        evs[w][1][(c2 * 4 + 3) * 64 + l] = e1[c2].w;
    }

    // ---- gather both rows in merge order (same-wave DS in-order)
    float v0[16], v1[16], pre0[16], pre1[16];
#pragma unroll
    for (int q = 0; q < 16; ++q) {
        const int ad = ((gx[q] & 15) << 6) | (gx[q] >> 4);
        v0[q] = evs[w][0][ad];
        v1[q] = evs[w][1][ad];
    }
    float run0 = 0.f, run1 = 0.f;
#pragma unroll
    for (int q = 0; q < 16; ++q) {
        pre0[q] = run0; run0 += v0[q];
        pre1[q] = run1; run1 += v1[q];
    }
    float i0 = run0, i1 = run1;
#pragma unroll
    for (int off = 1; off < 64; off <<= 1) {
        const float u0 = __shfl_up(i0, off);
        const float u1 = __shfl_up(i1, off);
        if (l >= off) { i0 += u0; i1 += u1; }
    }
    const float tot0 = __shfl(i0, 63), tot1 = __shfl(i1, 63);
    const float base0 = i0 - run0, base1 = i1 - run1;
#pragma unroll
    for (int q = 0; q < 16; ++q) {
        evs[w][0][q * 64 + l] = base0 + pre0[q];
        evs[w][1][q * 64 + l] = base1 + pre1[q];
    }

    float contrib = 0.f;
#pragma unroll
    for (int q = 0; q < 16; ++q) {
        const int m = rs[q];
        const int ad = ((m & 15) << 6) | (m >> 4);
        const float dn0 = tot0 - evs[w][0][ad];
        const float dn1 = tot1 - evs[w][1][ad];
        const float m2 = (gx[q] == oi) ? 1.f : 2.f;
        contrib -= m2 * (__logf(dn0) + __logf(dn1));
    }

#pragma unroll
    for (int off = 32; off; off >>= 1) contrib += __shfl_xor(contrib, off);
    if (l == 0) red[w] = contrib;
    __syncthreads();
    if (t == 0) {
        atomic_fx(acc, red[0] + red[1] + red[2] + red[3]);
        __threadfence();
        const unsigned done = atomicAdd(cnt, 1u);
        if (done == 255u) {
            const unsigned long long raw = atomicAdd(acc, 0ULL);
            const double tot = (double)(long long)raw / FPSCALE;
            out[0] = (float)(-tot / ((double)N * (double)(N - 1)));
        }
    }
}

// ================= FALLBACK PATH (round-5 fused, ~1.07 MB ws, proven) =================

__global__ __launch_bounds__(512) void k_prep_fb(
    const float* __restrict__ feat, const float* __restrict__ labels,
    ushort* __restrict__ fB, float* __restrict__ sq,
    float* __restrict__ slab, int* __restrict__ rank, int* __restrict__ sidx) {
    __shared__ float lab[NL];
    const int t = threadIdx.x;
    const int b = blockIdx.x;
    if (b < 2) {
        lab[t] = labels[t];
        lab[t + 512] = labels[t + 512];
        __syncthreads();
        const int j = b * 512 + t;
        const float lj = lab[j];
        int r = 0;
#pragma unroll 4
        for (int k = 0; k < NL; ++k) {
            const float lk = lab[k];
            r += (lk < lj) ? 1 : ((lk == lj && k < j) ? 1 : 0);
        }
        slab[r] = lj;
        sidx[r] = j;
        rank[j] = r;
        return;
    }
    const int l = t & 63;
    const int row = (b - 2) * 8 + (t >> 6);
    const float4 v = ((const float4*)(feat + (row & 1023) * 512 + (row >> 10) * 256))[l];
    float s = v.x * v.x + v.y * v.y + v.z * v.z + v.w * v.w;
#pragma unroll
    for (int off = 32; off; off >>= 1) s += __shfl_down(s, off);
    if (l == 0) sq[row] = s;
    ushort4 o;
    o.x = f2bf(v.x); o.y = f2bf(v.y); o.z = f2bf(v.z); o.w = f2bf(v.w);
    ((ushort4*)(fB + row * D))[l] = o;
}

__global__ __launch_bounds__(512) void k_fused(
    const ushort* __restrict__ fB, const float* __restrict__ sq,
    const float* __restrict__ slab, const int* __restrict__ sidx,
    const int* __restrict__ rank, const float* __restrict__ labels,
    float* __restrict__ bsum) {
    const int b = blockIdx.x;
    const int t = threadIdx.x;
    const int l = t & 63, w = t >> 6;
    const int tile0 = (b >> 1) * 16;
    const int half = b & 1;
    const int i0 = b * 8;

    __shared__ __align__(16) ushort erow[8][2048];
    __shared__ __align__(16) float slb[NL];
    __shared__ __align__(16) int sx[NL];
    __shared__ float red[8];

    ((float2*)slb)[t] = ((const float2*)slab)[t];
    ((int2*)sx)[t] = ((const int2*)sidx)[t];

    float contrib = 0.f;
    const int ko = (l >> 4) * 8;
    const ushort* arow = fB + (tile0 + (l & 15)) * D + ko;
    const int rg = l >> 4;

#pragma unroll
    for (int cp = 0; cp < 2; ++cp) {
        const int colbase = cp * 1024 + w * 128;
        const ushort* brow = fB + (colbase + (l & 15)) * D + ko;
        ffrag acc[8];
#pragma unroll
        for (int n = 0; n < 8; ++n) acc[n] = (ffrag){0.f, 0.f, 0.f, 0.f};
#pragma unroll
        for (int kk = 0; kk < 8; ++kk) {
            const bfrag a = *(const bfrag*)(arow + kk * 32);
#pragma unroll
            for (int n = 0; n < 8; ++n) {
                const bfrag bb = *(const bfrag*)(brow + n * 16 * D + kk * 32);
                acc[n] = __builtin_amdgcn_mfma_f32_16x16x32_bf16(a, bb, acc[n], 0, 0, 0);
            }
        }
        if ((rg >> 1) == half) {
#pragma unroll
            for (int v = 0; v < 4; ++v) {
                const int gi = tile0 + rg * 4 + v;
                const int r = gi - i0;
                const float sqi = sq[gi];
#pragma unroll
                for (int n = 0; n < 8; ++n) {
                    const int gj = colbase + n * 16 + (l & 15);
                    const float d2 = sqi + sq[gj] - 2.f * acc[n][v];
                    const float lg = -0.5f * sqrtf(fmaxf(d2, 0.f));
                    const bool diag = (gj == gi);
                    const float e = diag ? 0.f : expf(lg);
                    if (!diag) contrib += lg;
                    erow[r][gj] = f2bf(e);
                }
            }
        }
    }
    __syncthreads();

    const int gi = i0 + w;
    const int oi = gi & 1023;
    const float labi = labels[oi];
    const int pc = rank[oi];

    int sxv[16];
    float val[16], pre[16];
    const ushort* er = &erow[w][0];
#pragma unroll
    for (int c = 0; c < 4; ++c) {
        const int4 s4 = ((const int4*)sx)[l * 4 + c];
        sxv[c * 4 + 0] = s4.x; sxv[c * 4 + 1] = s4.y;
        sxv[c * 4 + 2] = s4.z; sxv[c * 4 + 3] = s4.w;
        val[c * 4 + 0] = bf2f(er[s4.x]) + bf2f(er[s4.x + 1024]);
        val[c * 4 + 1] = bf2f(er[s4.y]) + bf2f(er[s4.y + 1024]);
        val[c * 4 + 2] = bf2f(er[s4.z]) + bf2f(er[s4.z + 1024]);
        val[c * 4 + 3] = bf2f(er[s4.w]) + bf2f(er[s4.w + 1024]);
    }
    float run = 0.f;
#pragma unroll
    for (int q = 0; q < 16; ++q) { pre[q] = run; run += val[q]; }
    float inc = run;
#pragma unroll
    for (int off = 1; off < 64; off <<= 1) {
        const float u = __shfl_up(inc, off);
        if (l >= off) inc += u;
    }
    const float tot = __shfl(inc, 63);
    const float base = inc - run;
    float* E = (float*)&erow[w][0];
#pragma unroll
    for (int c = 0; c < 4; ++c) {
        float4 o;
        o.x = base + pre[c * 4 + 0];
        o.y = base + pre[c * 4 + 1];
        o.z = base + pre[c * 4 + 2];
        o.w = base + pre[c * 4 + 3];
        ((float4*)&E[l * 16])[c] = o;
    }

    const int lim = NL - pc;
#pragma unroll
    for (int q = 0; q < 16; ++q) {
        const int p = l * 16 + q;
        const float tq = fabsf(labi - slb[p]);
        int lo = 0;
#pragma unroll
        for (int step = 512; step; step >>= 1) {
            const int cand = lo + step;
            const int ix = max(min(cand - 1, pc - 1), 0);
            const bool ok = (cand <= pc) && (fabsf(labi - slb[ix]) >= tq);
            lo = ok ? cand : lo;
        }
        int hi = 0;
#pragma unroll
        for (int step = 512; step; step >>= 1) {
            const int cand = hi + step;
            const int ix = min(pc + cand - 1, NL - 1);
            const bool ok = (cand <= lim) && (fabsf(labi - slb[ix]) < tq);
            hi = ok ? cand : hi;
        }
        const int hl = pc + hi;
        const float Eh = (hl == NL) ? tot : E[hl];
        const float dn = tot - (Eh - E[lo]);
        const float m2 = (sxv[q] == oi) ? 1.f : 2.f;
        contrib -= m2 * logf(dn);
    }

#pragma unroll
    for (int off = 32; off; off >>= 1) contrib += __shfl_xor(contrib, off);
    if (l == 0) red[w] = contrib;
    __syncthreads();
    if (t == 0) {
        float sb = 0.f;
#pragma unroll
        for (int q = 0; q < 8; ++q) sb += red[q];
        bsum[b] = sb;
    }
}

__global__ void k_final_fb(const float* __restrict__ bs, float* __restrict__ out) {
    __shared__ double rd[4];
    const int t = threadIdx.x;
    double s = (double)bs[t];
#pragma unroll
    for (int off = 32; off; off >>= 1) s += __shfl_down(s, off);
    if ((t & 63) == 0) rd[t >> 6] = s;
    __syncthreads();
    if (t == 0) {
        const double tot = rd[0] + rd[1] + rd[2] + rd[3];
        out[0] = (float)(-tot / ((double)N * (double)(N - 1)));
    }
}

extern "C" void kernel_launch(void* const* d_in, const int* in_sizes, int n_in,
                              void* d_out, int out_size, void* d_ws, size_t ws_size,
                              hipStream_t stream) {
    const float* feat = (const float*)d_in[0];
    const float* labels = (const float*)d_in[1];
    char* ws = (char*)d_ws;

    if (ws_size >= 9457680ULL) {
        ushort* fB = (ushort*)ws;
        float* evG = (float*)(ws + 1048576);
        float* sq = (float*)(ws + 9437184);
        float* slab = (float*)(ws + 9445376);
        int* sidx = (int*)(ws + 9449472);
        int* rank = (int*)(ws + 9453568);
        unsigned long long* acc = (unsigned long long*)(ws + 9457664);
        unsigned int* cnt = (unsigned int*)(ws + 9457672);

        k_prep4<<<272, 512, 0, stream>>>(feat, labels, fB, sq, slab, rank, sidx, acc, cnt);
        k_G<<<256, 512, 0, stream>>>(fB, sq, evG, acc);
        k_S5<<<256, 256, 0, stream>>>(evG, slab, sidx, rank, acc, cnt, (float*)d_out);
    } else {
        ushort* fB = (ushort*)ws;
        float* sq = (float*)(ws + 1048576);
        float* slab = (float*)(ws + 1056768);
        int* sidx = (int*)(ws + 1060864);
        int* rank = (int*)(ws + 1064960);
        float* bsum = (float*)(ws + 1069056);

        k_prep_fb<<<258, 512, 0, stream>>>(feat, labels, fB, sq, slab, rank, sidx);
        k_fused<<<256, 512, 0, stream>>>(fB, sq, slab, sidx, rank, labels, bsum);
        k_final_fb<<<1, 256, 0, stream>>>(bsum, (float*)d_out);
    }
}